// Round 7
// baseline (2903.679 us; speedup 1.0000x reference)
//
#include <hip/hip_runtime.h>
#include <math.h>

constexpr int BB  = 4;
constexpr int NN  = 4096;
constexpr int KK  = 20;
constexpr int NKK = NN * KK;     // 81920 positions per batch
constexpr int TPOS = BB * NKK;   // 327680 total positions
constexpr int NMASK = NN - 1;

#define DEVFN __device__ __forceinline__

DEVFN float lrelu_f(float v) { return v >= 0.f ? v : 0.2f * v; }
DEVFN unsigned fenc(float f) { unsigned u = __float_as_uint(f); return (u & 0x80000000u) ? ~u : (u | 0x80000000u); }
DEVFN float fdec(unsigned k) { unsigned u = (k & 0x80000000u) ? (k & 0x7fffffffu) : ~k; return __uint_as_float(u); }

// ---------------- kNN: top-20 by pd, bit-exact reference formula ----------------
// 16 threads/query (interleaved slices), shared-threshold guard (exact), branchless insert,
// u64-key 16-way merge with stride-21 padding. SoA float3 staging (48KB -> 3 blocks/CU).
template<int CSTRIDE>
__global__ __launch_bounds__(256) void knn_kernel(const float* __restrict__ xin, int* __restrict__ idxout)
{
    __shared__ float smem[12288];              // 48 KB: sx|sy|sz ; reused as u64 merge buffer
    float* sx = smem; float* sy = smem + 4096; float* sz = smem + 8192;
    const int tid = threadIdx.x;
    const int b  = blockIdx.x >> 8;            // 256 blocks per batch
    const int q0 = (blockIdx.x & 255) * 16;    // 16 queries per block
    for (int i = tid; i < NN; i += 256) {
        const float4 rc = *reinterpret_cast<const float4*>(xin + (size_t)(b*NN + i) * CSTRIDE);
        sx[i] = rc.x; sy[i] = rc.y; sz[i] = rc.z;
    }
    __syncthreads();
    const int qo = tid >> 4;                   // query within block (0..15)
    const int sl = tid & 15;                   // slice (0..15)
    const int qi = q0 + qo;                    // within-batch query index
    const float qx = sx[qi], qy = sy[qi], qz = sz[qi];
    const float nxx = -__fadd_rn(__fadd_rn(__fmul_rn(qx,qx), __fmul_rn(qy,qy)), __fmul_rn(qz,qz));
    float vals[KK]; int inds[KK];
#pragma unroll
    for (int k = 0; k < KK; ++k) { vals[k] = -INFINITY; inds[k] = 0; }
    float T = -INFINITY;                       // group lower bound on final 20th (exact-safe)
    float cx = sx[sl], cy = sy[sl], cz = sz[sl];
    for (int t = 0; t < NN/16; ++t) {
        const int mn = sl + (((t+1) & (NN/16 - 1)) << 4);   // prefetch next slot
        const float nx = sx[mn], ny = sy[mn], nz = sz[mn];
        const int m = sl + (t << 4);
        float cw  = __fadd_rn(__fadd_rn(__fmul_rn(cx,cx), __fmul_rn(cy,cy)), __fmul_rn(cz,cz));
        float dot = __fadd_rn(__fadd_rn(__fmul_rn(qx,cx), __fmul_rn(qy,cy)), __fmul_rn(qz,cz));
        float pd  = __fsub_rn(__fsub_rn(nxx, __fmul_rn(-2.f, dot)), cw);
        if (pd >= T) {                         // T <= final-20th: drops safe; ties enter
#pragma unroll
            for (int k = KK-1; k >= 1; --k) {  // strict compares keep stable tie-break
                bool ck  = pd > vals[k];
                bool ckm = pd > vals[k-1];
                vals[k] = ck ? (ckm ? vals[k-1] : pd) : vals[k];
                inds[k] = ck ? (ckm ? inds[k-1] : m) : inds[k];
            }
            bool c0 = pd > vals[0];
            vals[0] = c0 ? pd : vals[0];
            inds[0] = c0 ? m  : inds[0];
        }
        if ((t & 3) == 3) {                    // refresh shared threshold (monotone, stale-safe)
            float tt = vals[KK-1];
            tt = fmaxf(tt, __shfl_xor(tt, 1, 64));
            tt = fmaxf(tt, __shfl_xor(tt, 2, 64));
            tt = fmaxf(tt, __shfl_xor(tt, 4, 64));
            tt = fmaxf(tt, __shfl_xor(tt, 8, 64));
            T = tt;
        }
        cx = nx; cy = ny; cz = nz;
    }
    __syncthreads();                           // done with coords
    unsigned long long* mrg = reinterpret_cast<unsigned long long*>(smem);
    constexpr int MS = KK + 1;                 // stride 21: no bank alignment
    {
        unsigned long long* my = mrg + (size_t)(qo*16 + sl)*MS;
#pragma unroll
        for (int k = 0; k < KK; ++k)
            my[k] = ((unsigned long long)fenc(vals[k]) << 32) | (unsigned)(NN-1 - inds[k]);
    }
    __syncthreads();
    if (sl == 0) {                             // merge 16 sorted lists (stable: idx tie -> lower)
        int head[16];
#pragma unroll
        for (int s = 0; s < 16; ++s) head[s] = 0;
        unsigned long long* base = mrg + (size_t)qo*16*MS;
        int* op = idxout + ((size_t)(b*NN + qi)) * KK;
        for (int k = 0; k < KK; ++k) {
            unsigned long long best = 0; int bs = 0;
#pragma unroll
            for (int s = 0; s < 16; ++s) {
                unsigned long long kv = base[s*MS + head[s]];
                if (kv > best) { best = kv; bs = s; }
            }
#pragma unroll
            for (int s = 0; s < 16; ++s) head[s] += (s == bs) ? 1 : 0;
            op[k] = (NN-1) - (int)(best & 0xFFFFFFFFull);
        }
    }
}

// ---------------- stage 1 pass A: conv1 (8->64) stats only (f64 accum) ----------------
__global__ __launch_bounds__(64) void s1a_kernel(const float* __restrict__ x, const int* __restrict__ idx,
    const float* __restrict__ w1, double* __restrict__ ssum, double* __restrict__ ssq)
{
    const int lane = threadIdx.x;
    float wr[8];
#pragma unroll
    for (int c = 0; c < 8; ++c) wr[c] = w1[lane*8 + c];
    const int g0 = blockIdx.x * 8;            // global row (b*NN+n), 8 rows per block
    const int b = g0 / NN;
    double lsum = 0.0, lsq = 0.0;
    for (int ni = 0; ni < 8; ++ni) {
        const int g = g0 + ni;
        const float4 ct = *reinterpret_cast<const float4*>(x + (size_t)g*4);
        for (int k = 0; k < KK; ++k) {
            const int j = idx[(size_t)g*KK + k] & NMASK;
            const float4 nb = *reinterpret_cast<const float4*>(x + (size_t)(b*NN + j)*4);
            float o1 = wr[0]*(nb.x-ct.x) + wr[1]*(nb.y-ct.y) + wr[2]*(nb.z-ct.z) + wr[3]*(nb.w-ct.w)
                     + wr[4]*ct.x + wr[5]*ct.y + wr[6]*ct.z + wr[7]*ct.w;
            lsum += (double)o1; lsq += (double)o1*(double)o1;
        }
    }
    atomicAdd(&ssum[b*64+lane], lsum);
    atomicAdd(&ssq [b*64+lane], lsq);
}

// ---------------- stage 1 pass B: recompute conv1, norm+lrelu, conv2 (64->64), stats2 + max_k ----------------
__global__ __launch_bounds__(64) void s1b_kernel(const float* __restrict__ x, const int* __restrict__ idx,
    const float* __restrict__ w1, const float* __restrict__ w2,
    const float* __restrict__ m1, const float* __restrict__ r1,
    float* __restrict__ xraw, double* __restrict__ ssum, double* __restrict__ ssq)
{
    __shared__ float sh[64];
    const int lane = threadIdx.x;
    float wr1[8];
#pragma unroll
    for (int c = 0; c < 8; ++c) wr1[c] = w1[lane*8 + c];
    float wr2[64];
#pragma unroll
    for (int c = 0; c < 64; ++c) wr2[c] = w2[lane*64 + c];
    const int g0 = blockIdx.x * 8;
    const int b = g0 / NN;
    const float mm = m1[b*64+lane], rr = r1[b*64+lane];
    double lsum = 0.0, lsq = 0.0;
    for (int ni = 0; ni < 8; ++ni) {
        const int g = g0 + ni;
        const float4 ct = *reinterpret_cast<const float4*>(x + (size_t)g*4);
        float vmax = -INFINITY;
        for (int k = 0; k < KK; ++k) {
            const int j = idx[(size_t)g*KK + k] & NMASK;
            const float4 nb = *reinterpret_cast<const float4*>(x + (size_t)(b*NN + j)*4);
            float o1 = wr1[0]*(nb.x-ct.x) + wr1[1]*(nb.y-ct.y) + wr1[2]*(nb.z-ct.z) + wr1[3]*(nb.w-ct.w)
                     + wr1[4]*ct.x + wr1[5]*ct.y + wr1[6]*ct.z + wr1[7]*ct.w;
            float h = lrelu_f((o1 - mm) * rr);
            __syncthreads();                  // protect prior reads
            sh[lane] = h;
            __syncthreads();
            float acc = 0.f;
#pragma unroll
            for (int c = 0; c < 64; c += 4) {
                const float4 hv = *reinterpret_cast<const float4*>(&sh[c]);
                acc += wr2[c]*hv.x + wr2[c+1]*hv.y + wr2[c+2]*hv.z + wr2[c+3]*hv.w;
            }
            vmax = fmaxf(vmax, acc);
            lsum += (double)acc; lsq += (double)acc*(double)acc;
        }
        xraw[(size_t)g*64 + lane] = vmax;
    }
    atomicAdd(&ssum[b*64+lane], lsum);
    atomicAdd(&ssq [b*64+lane], lsq);
}

// ---------------- gather conv (128->64) stats only (conv3 pass A) ----------------
__global__ __launch_bounds__(64) void s2a_kernel(const float* __restrict__ xin, const int* __restrict__ idx,
    const float* __restrict__ w, double* __restrict__ ssum, double* __restrict__ ssq)
{
    __shared__ float sf[128];
    const int lane = threadIdx.x;
    float wr[128];
#pragma unroll
    for (int c = 0; c < 128; ++c) wr[c] = w[lane*128 + c];
    const int g0 = blockIdx.x * 8;
    const int b = g0 / NN;
    double lsum = 0.0, lsq = 0.0;
    for (int ni = 0; ni < 8; ++ni) {
        const int g = g0 + ni;
        const float ctl = xin[(size_t)g*64 + lane];
        for (int k = 0; k < KK; ++k) {
            const int j = idx[(size_t)g*KK + k] & NMASK;
            const float nbl = xin[(size_t)(b*NN + j)*64 + lane];
            __syncthreads();
            sf[lane] = nbl - ctl;
            sf[64+lane] = ctl;
            __syncthreads();
            float acc = 0.f;
#pragma unroll
            for (int c = 0; c < 128; c += 4) {
                const float4 fv = *reinterpret_cast<const float4*>(&sf[c]);
                acc += wr[c]*fv.x + wr[c+1]*fv.y + wr[c+2]*fv.z + wr[c+3]*fv.w;
            }
            lsum += (double)acc; lsq += (double)acc*(double)acc;
        }
    }
    atomicAdd(&ssum[b*64+lane], lsum);
    atomicAdd(&ssq [b*64+lane], lsq);
}

// ---------------- stage 2 pass B: recompute conv3, norm+lrelu, conv4 (64->64), stats4 + max_k ----------------
__global__ __launch_bounds__(64) void s2b_kernel(const float* __restrict__ xin, const int* __restrict__ idx,
    const float* __restrict__ w3, const float* __restrict__ w4,
    const float* __restrict__ m3, const float* __restrict__ r3,
    float* __restrict__ xraw, double* __restrict__ ssum, double* __restrict__ ssq)
{
    __shared__ float sf[128];
    __shared__ float sh[64];
    const int lane = threadIdx.x;
    float wr3[128];
#pragma unroll
    for (int c = 0; c < 128; ++c) wr3[c] = w3[lane*128 + c];
    float wr4[64];
#pragma unroll
    for (int c = 0; c < 64; ++c) wr4[c] = w4[lane*64 + c];
    const int g0 = blockIdx.x * 8;
    const int b = g0 / NN;
    const float mm = m3[b*64+lane], rr = r3[b*64+lane];
    double lsum = 0.0, lsq = 0.0;
    for (int ni = 0; ni < 8; ++ni) {
        const int g = g0 + ni;
        const float ctl = xin[(size_t)g*64 + lane];
        float vmax = -INFINITY;
        for (int k = 0; k < KK; ++k) {
            const int j = idx[(size_t)g*KK + k] & NMASK;
            const float nbl = xin[(size_t)(b*NN + j)*64 + lane];
            __syncthreads();
            sf[lane] = nbl - ctl;
            sf[64+lane] = ctl;
            __syncthreads();
            float o3 = 0.f;
#pragma unroll
            for (int c = 0; c < 128; c += 4) {
                const float4 fv = *reinterpret_cast<const float4*>(&sf[c]);
                o3 += wr3[c]*fv.x + wr3[c+1]*fv.y + wr3[c+2]*fv.z + wr3[c+3]*fv.w;
            }
            float h = lrelu_f((o3 - mm) * rr);
            __syncthreads();
            sh[lane] = h;
            __syncthreads();
            float acc = 0.f;
#pragma unroll
            for (int c = 0; c < 64; c += 4) {
                const float4 hv = *reinterpret_cast<const float4*>(&sh[c]);
                acc += wr4[c]*hv.x + wr4[c+1]*hv.y + wr4[c+2]*hv.z + wr4[c+3]*hv.w;
            }
            vmax = fmaxf(vmax, acc);
            lsum += (double)acc; lsq += (double)acc*(double)acc;
        }
        xraw[(size_t)g*64 + lane] = vmax;
    }
    atomicAdd(&ssum[b*64+lane], lsum);
    atomicAdd(&ssq [b*64+lane], lsq);
}

// ---------------- stage 3: conv5 (128->64) single pass: stats5 + max_k ----------------
__global__ __launch_bounds__(64) void s3_kernel(const float* __restrict__ xin, const int* __restrict__ idx,
    const float* __restrict__ w, float* __restrict__ xraw, double* __restrict__ ssum, double* __restrict__ ssq)
{
    __shared__ float sf[128];
    const int lane = threadIdx.x;
    float wr[128];
#pragma unroll
    for (int c = 0; c < 128; ++c) wr[c] = w[lane*128 + c];
    const int g0 = blockIdx.x * 8;
    const int b = g0 / NN;
    double lsum = 0.0, lsq = 0.0;
    for (int ni = 0; ni < 8; ++ni) {
        const int g = g0 + ni;
        const float ctl = xin[(size_t)g*64 + lane];
        float vmax = -INFINITY;
        for (int k = 0; k < KK; ++k) {
            const int j = idx[(size_t)g*KK + k] & NMASK;
            const float nbl = xin[(size_t)(b*NN + j)*64 + lane];
            __syncthreads();
            sf[lane] = nbl - ctl;
            sf[64+lane] = ctl;
            __syncthreads();
            float acc = 0.f;
#pragma unroll
            for (int c = 0; c < 128; c += 4) {
                const float4 fv = *reinterpret_cast<const float4*>(&sf[c]);
                acc += wr[c]*fv.x + wr[c+1]*fv.y + wr[c+2]*fv.z + wr[c+3]*fv.w;
            }
            vmax = fmaxf(vmax, acc);
            lsum += (double)acc; lsq += (double)acc*(double)acc;
        }
        xraw[(size_t)g*64 + lane] = vmax;
    }
    atomicAdd(&ssum[b*64+lane], lsum);
    atomicAdd(&ssq [b*64+lane], lsq);
}

// ---------------- stats finalize: f64 sum/sq -> f32 mean/rstd ----------------
__global__ void fin_kernel(const double* __restrict__ ssum, const double* __restrict__ ssq,
                           float* __restrict__ meanp, float* __restrict__ rstdp, int total, double invn)
{
    int t = blockIdx.x*256 + threadIdx.x;
    if (t >= total) return;
    double m = ssum[t]*invn;
    double v = ssq[t]*invn - m*m;
    meanp[t] = (float)m;
    rstdp[t] = (float)(1.0 / sqrt(v + 1e-5));
}

// ---------------- in-place finalize of x raw max: x = lrelu((x-m)*r) ----------------
__global__ void finx_kernel(float* __restrict__ xv, const float* __restrict__ m, const float* __restrict__ r)
{
    int t = blockIdx.x*256 + threadIdx.x;   // B*NN*64 = 1048576
    int c = t & 63;
    int b = t >> 18;                        // NN*64 = 2^18
    float v = xv[t];
    xv[t] = lrelu_f((v - m[b*64+c]) * r[b*64+c]);
}

// weight transpose: wT[c*O + o] = w[o*rs + off + c]
__global__ void transw_kernel(const float* __restrict__ w, float* __restrict__ wT, int O, int C, int rs, int off)
{
    int t = blockIdx.x*256 + threadIdx.x;
    if (t >= O*C) return;
    int o = t % O, c = t / O;
    wT[t] = w[(size_t)o*rs + off + c];
}

// conv6: 192->1024 over n, reduced on the fly (sum/sumsq/max per (b,o)); output never materialized
__global__ __launch_bounds__(256) void conv6_kernel(
    const float* __restrict__ x1, const float* __restrict__ x2, const float* __restrict__ x3,
    const float* __restrict__ wT, double* __restrict__ s6sum, double* __restrict__ s6sq, unsigned* __restrict__ s6max)
{
    __shared__ float si[32][192];
    const int b = blockIdx.z, nbase = blockIdx.x*32;
    const int o = blockIdx.y*256 + threadIdx.x;
    for (int i = threadIdx.x; i < 32*192; i += 256) {
        int nl = i/192, c = i%192;
        size_t base = (size_t)(b*NN + nbase + nl)*64;
        si[nl][c] = (c < 64) ? x1[base + c] : (c < 128) ? x2[base + c - 64] : x3[base + c - 128];
    }
    __syncthreads();
    float acc[32];
#pragma unroll
    for (int n = 0; n < 32; ++n) acc[n] = 0.f;
    for (int c = 0; c < 192; ++c) {
        float wv = wT[(size_t)c*1024 + o];
#pragma unroll
        for (int n = 0; n < 32; ++n) acc[n] = fmaf(wv, si[n][c], acc[n]);
    }
    double ps = 0.0, pq = 0.0; float pm = -INFINITY;
#pragma unroll
    for (int n = 0; n < 32; ++n) { ps += (double)acc[n]; pq += (double)acc[n]*(double)acc[n]; pm = fmaxf(pm, acc[n]); }
    atomicAdd(&s6sum[b*1024+o], ps);
    atomicAdd(&s6sq [b*1024+o], pq);
    atomicMax(&s6max[b*1024+o], fenc(pm));
}

__global__ void gfin_kernel(const double* __restrict__ s6sum, const double* __restrict__ s6sq,
                            const unsigned* __restrict__ s6max, float* __restrict__ g)
{
    int t = blockIdx.x*256 + threadIdx.x;   // 4096
    double m = s6sum[t] * (1.0/4096.0);
    double v = s6sq[t] * (1.0/4096.0) - m*m;
    float rs = (float)(1.0 / sqrt(v + 1e-5));
    g[t] = lrelu_f((fdec(s6max[t]) - (float)m) * rs);   // lrelu∘norm commutes with max over n
}

// gbias[b][o] = sum_{c<1024} w7[o][c] * g[b][c]
__global__ __launch_bounds__(256) void gbias_kernel(const float* __restrict__ w7, const float* __restrict__ g,
                                                    float* __restrict__ gbias)
{
    const int b = blockIdx.y;
    const int o = blockIdx.x*256 + threadIdx.x;
    const float* wr = w7 + (size_t)o*1216;
    const float* gv = g + b*1024;
    float acc = 0.f;
    for (int c = 0; c < 1024; c += 4) {
        float4 wv = *reinterpret_cast<const float4*>(&wr[c]);
        float4 gg = *reinterpret_cast<const float4*>(&gv[c]);
        acc = fmaf(wv.x, gg.x, fmaf(wv.y, gg.y, fmaf(wv.z, gg.z, fmaf(wv.w, gg.w, acc))));
    }
    gbias[b*512+o] = acc;
}

// conv7 pass A: 192(cat)+gbias -> 512, stats only (no store)
__global__ __launch_bounds__(256) void conv7a_kernel(
    const float* __restrict__ x1, const float* __restrict__ x2, const float* __restrict__ x3,
    const float* __restrict__ wT, const float* __restrict__ gbias,
    double* __restrict__ ssum, double* __restrict__ ssq)
{
    __shared__ float si[32][192];
    const int b = blockIdx.z, nbase = blockIdx.x*32;
    const int o = blockIdx.y*256 + threadIdx.x;
    for (int i = threadIdx.x; i < 32*192; i += 256) {
        int nl = i/192, c = i%192;
        size_t base = (size_t)(b*NN + nbase + nl)*64;
        si[nl][c] = (c < 64) ? x1[base + c] : (c < 128) ? x2[base + c - 64] : x3[base + c - 128];
    }
    __syncthreads();
    float acc[32];
    const float gb = gbias[b*512 + o];
#pragma unroll
    for (int n = 0; n < 32; ++n) acc[n] = gb;
    for (int c = 0; c < 192; ++c) {
        float wv = wT[(size_t)c*512 + o];
#pragma unroll
        for (int n = 0; n < 32; ++n) acc[n] = fmaf(wv, si[n][c], acc[n]);
    }
    double ps = 0.0, pq = 0.0;
#pragma unroll
    for (int n = 0; n < 32; ++n) { ps += (double)acc[n]; pq += (double)acc[n]*(double)acc[n]; }
    atomicAdd(&ssum[b*512+o], ps);
    atomicAdd(&ssq [b*512+o], pq);
}

// conv7+conv8 fused pass B: recompute conv7, norm+lrelu -> h7 (LDS), conv8 -> out8 + stats8
__global__ __launch_bounds__(256) void conv78_kernel(
    const float* __restrict__ x1, const float* __restrict__ x2, const float* __restrict__ x3,
    const float* __restrict__ wT7, const float* __restrict__ wT8, const float* __restrict__ gbias,
    const float* __restrict__ m7, const float* __restrict__ r7,
    float* __restrict__ out8, double* __restrict__ ssum, double* __restrict__ ssq)
{
    __shared__ float si[16][192];    // 12 KB
    __shared__ float h7[16][512];    // 32 KB
    const int b = blockIdx.y, nbase = blockIdx.x*16;
    const int tid = threadIdx.x;
    for (int i = tid; i < 16*192; i += 256) {
        int nl = i/192, c = i%192;
        size_t base = (size_t)(b*NN + nbase + nl)*64;
        si[nl][c] = (c < 64) ? x1[base + c] : (c < 128) ? x2[base + c - 64] : x3[base + c - 128];
    }
    __syncthreads();
#pragma unroll
    for (int oo = 0; oo < 512; oo += 256) {
        const int o = oo + tid;
        const float gb = gbias[b*512+o], mm = m7[b*512+o], rr = r7[b*512+o];
        float acc[16];
#pragma unroll
        for (int n = 0; n < 16; ++n) acc[n] = gb;
        for (int c = 0; c < 192; ++c) {
            float wv = wT7[(size_t)c*512 + o];
#pragma unroll
            for (int n = 0; n < 16; ++n) acc[n] = fmaf(wv, si[n][c], acc[n]);
        }
#pragma unroll
        for (int n = 0; n < 16; ++n) h7[n][o] = lrelu_f((acc[n] - mm) * rr);
    }
    __syncthreads();
    const int o = tid;
    float acc8[16];
#pragma unroll
    for (int n = 0; n < 16; ++n) acc8[n] = 0.f;
    for (int c = 0; c < 512; ++c) {
        float wv = wT8[(size_t)c*256 + o];
#pragma unroll
        for (int n = 0; n < 16; ++n) acc8[n] = fmaf(wv, h7[n][c], acc8[n]);
    }
    double ps = 0.0, pq = 0.0;
#pragma unroll
    for (int n = 0; n < 16; ++n) {
        out8[(size_t)(b*NN + nbase + n)*256 + o] = acc8[n];
        ps += (double)acc8[n]; pq += (double)acc8[n]*(double)acc8[n];
    }
    atomicAdd(&ssum[b*256+o], ps);
    atomicAdd(&ssq [b*256+o], pq);
}

// conv9: 256 -> 2, output (B,N,2)
__global__ __launch_bounds__(256) void conv9_kernel(const float* __restrict__ in8,
    const float* __restrict__ meanp, const float* __restrict__ rstdp,
    const float* __restrict__ w9, float* __restrict__ outp)
{
    const int lane = threadIdx.x & 63, wv = threadIdx.x >> 6;
    const int ng = blockIdx.x*4 + wv;
    const int b = ng / NN;
    const int c0 = lane*4;
    const float4 v4 = *reinterpret_cast<const float4*>(&in8[(size_t)ng*256 + c0]);
    float vv[4] = {v4.x, v4.y, v4.z, v4.w};
    float a0 = 0.f, a1 = 0.f;
#pragma unroll
    for (int i = 0; i < 4; ++i) {
        int c = c0 + i;
        float a = lrelu_f((vv[i] - meanp[b*256+c]) * rstdp[b*256+c]);
        a0 = fmaf(w9[c],     a, a0);
        a1 = fmaf(w9[256+c], a, a1);
    }
#pragma unroll
    for (int off = 32; off > 0; off >>= 1) {
        a0 += __shfl_down(a0, off, 64);
        a1 += __shfl_down(a1, off, 64);
    }
    if (lane == 0) { outp[(size_t)ng*2 + 0] = a0; outp[(size_t)ng*2 + 1] = a1; }
}

extern "C" void kernel_launch(void* const* d_in, const int* in_sizes, int n_in,
                              void* d_out, int out_size, void* d_ws, size_t ws_size,
                              hipStream_t stream)
{
    const float* x  = (const float*)d_in[0];
    const float* w1 = (const float*)d_in[1];
    const float* w2 = (const float*)d_in[2];
    const float* w3 = (const float*)d_in[3];
    const float* w4 = (const float*)d_in[4];
    const float* w5 = (const float*)d_in[5];
    const float* w6 = (const float*)d_in[6];
    const float* w7 = (const float*)d_in[7];
    const float* w8 = (const float*)d_in[8];
    const float* w9 = (const float*)d_in[9];
    float* outp = (float*)d_out;

    char* ws = (char*)d_ws;
    size_t off = 0;
    auto alloc = [&](size_t bytes) -> void* {
        void* p = ws + off;
        off = (off + bytes + 255) & ~(size_t)255;
        return p;
    };
    // f64 stats block + u32 max block: contiguous, one memset
    double* dstats = (double*)alloc((size_t)16896 * 8);      // 135168 B (multiple of 256)
    unsigned* u6max = (unsigned*)alloc((size_t)4096 * 4);    // 16384 B, contiguous after dstats
    float* fstats = (float*)alloc((size_t)14848 * 4);        // means/rstds/g/gbias
    int*   idxb  = (int*)  alloc((size_t)TPOS * 4);          // 1.31 MB
    float* wT6   = (float*)alloc((size_t)1024*192*4);
    float* wT7   = (float*)alloc((size_t)512*192*4);
    float* wT8   = (float*)alloc((size_t)256*512*4);
    float* x1v   = (float*)alloc((size_t)BB*NN*64*4);
    float* x2v   = (float*)alloc((size_t)BB*NN*64*4);
    float* x3v   = (float*)alloc((size_t)BB*NN*64*4);
    float* out8  = (float*)alloc((size_t)BB*NN*256*4);       // total ~32.6 MB

    // dstats layout (doubles): d1..d5 at s*512 (sum256|sq256); d6 @2560 (4096|4096);
    // d7 @10752 (2048|2048); d8 @14848 (1024|1024)
    double* d1 = dstats;           double* d2 = dstats + 512;
    double* d3 = dstats + 1024;    double* d4 = dstats + 1536;
    double* d5 = dstats + 2048;
    double* d6sum = dstats + 2560; double* d6sq = d6sum + 4096;
    double* d7sum = dstats + 10752; double* d7sq = d7sum + 2048;
    double* d8sum = dstats + 14848; double* d8sq = d8sum + 1024;
    // fstats layout (floats): m/r for s1..s5 at s*512; g @2560; m7 @6656; r7 @8704; gbias @10752; m8 @12800; r8 @13824
    float* m1 = fstats;        float* r1 = fstats + 256;
    float* m2 = fstats + 512;  float* r2 = fstats + 768;
    float* m3 = fstats + 1024; float* r3 = fstats + 1280;
    float* m4 = fstats + 1536; float* r4 = fstats + 1792;
    float* m5 = fstats + 2048; float* r5 = fstats + 2304;
    float* g  = fstats + 2560;
    float* m7 = fstats + 6656; float* r7 = fstats + 8704;
    float* gbias = fstats + 10752;
    float* m8 = fstats + 12800; float* r8 = fstats + 13824;

    hipMemsetAsync(dstats, 0, (size_t)16896*8 + (size_t)4096*4, stream);  // f64 stats + u6max

    transw_kernel<<<768, 256, 0, stream>>>(w6, wT6, 1024, 192, 192, 0);
    transw_kernel<<<384, 256, 0, stream>>>(w7, wT7, 512, 192, 1216, 1024);
    transw_kernel<<<512, 256, 0, stream>>>(w8, wT8, 256, 512, 512, 0);

    // ---- stage 1 ----
    knn_kernel<4><<<1024, 256, 0, stream>>>(x, idxb);
    s1a_kernel<<<2048, 64, 0, stream>>>(x, idxb, w1, d1, d1+256);
    fin_kernel<<<1, 256, 0, stream>>>(d1, d1+256, m1, r1, 256, 1.0/81920.0);
    s1b_kernel<<<2048, 64, 0, stream>>>(x, idxb, w1, w2, m1, r1, x1v, d2, d2+256);
    fin_kernel<<<1, 256, 0, stream>>>(d2, d2+256, m2, r2, 256, 1.0/81920.0);
    finx_kernel<<<4096, 256, 0, stream>>>(x1v, m2, r2);

    // ---- stage 2 ----
    knn_kernel<64><<<1024, 256, 0, stream>>>(x1v, idxb);
    s2a_kernel<<<2048, 64, 0, stream>>>(x1v, idxb, w3, d3, d3+256);
    fin_kernel<<<1, 256, 0, stream>>>(d3, d3+256, m3, r3, 256, 1.0/81920.0);
    s2b_kernel<<<2048, 64, 0, stream>>>(x1v, idxb, w3, w4, m3, r3, x2v, d4, d4+256);
    fin_kernel<<<1, 256, 0, stream>>>(d4, d4+256, m4, r4, 256, 1.0/81920.0);
    finx_kernel<<<4096, 256, 0, stream>>>(x2v, m4, r4);

    // ---- stage 3 ----
    knn_kernel<64><<<1024, 256, 0, stream>>>(x2v, idxb);
    s3_kernel<<<2048, 64, 0, stream>>>(x2v, idxb, w5, x3v, d5, d5+256);
    fin_kernel<<<1, 256, 0, stream>>>(d5, d5+256, m5, r5, 256, 1.0/81920.0);
    finx_kernel<<<4096, 256, 0, stream>>>(x3v, m5, r5);

    // ---- global feature ----
    conv6_kernel<<<dim3(128, 4, 4), 256, 0, stream>>>(x1v, x2v, x3v, wT6, d6sum, d6sq, u6max);
    gfin_kernel<<<16, 256, 0, stream>>>(d6sum, d6sq, u6max, g);
    gbias_kernel<<<dim3(2, 4), 256, 0, stream>>>(w7, g, gbias);

    // ---- head ----
    conv7a_kernel<<<dim3(128, 2, 4), 256, 0, stream>>>(x1v, x2v, x3v, wT7, gbias, d7sum, d7sq);
    fin_kernel<<<8, 256, 0, stream>>>(d7sum, d7sq, m7, r7, 2048, 1.0/4096.0);
    conv78_kernel<<<dim3(256, 4), 256, 0, stream>>>(x1v, x2v, x3v, wT7, wT8, gbias, m7, r7, out8, d8sum, d8sq);
    fin_kernel<<<4, 256, 0, stream>>>(d8sum, d8sq, m8, r8, 1024, 1.0/4096.0);
    conv9_kernel<<<4096, 256, 0, stream>>>(out8, m8, r8, w9, outp);
}

// Round 8
// 2301.014 us; speedup vs baseline: 1.2619x; 1.2619x over previous
//
#include <hip/hip_runtime.h>
#include <math.h>

constexpr int BB  = 4;
constexpr int NN  = 4096;
constexpr int KK  = 20;
constexpr int NKK = NN * KK;     // 81920 positions per batch
constexpr int TPOS = BB * NKK;   // 327680 total positions
constexpr int NMASK = NN - 1;

#define DEVFN __device__ __forceinline__

DEVFN float lrelu_f(float v) { return v >= 0.f ? v : 0.2f * v; }
DEVFN unsigned fenc(float f) { unsigned u = __float_as_uint(f); return (u & 0x80000000u) ? ~u : (u | 0x80000000u); }
DEVFN float fdec(unsigned k) { unsigned u = (k & 0x80000000u) ? (k & 0x7fffffffu) : ~k; return __uint_as_float(u); }

// ---------------- kNN via LDS radix-select: top-20 by pd, bit-exact reference formula ----------------
// Per query (16/block, sequential): all 256 threads compute 16 dists -> fenc keys in LDS;
// 2-level 8-bit radix narrows to the exact 20th key W; extract keys>=W; rank by
// (key<<32)|(NN-1-idx) u64 (value desc, idx asc) == jax.lax.top_k stable order.
template<int CSTRIDE>
__global__ __launch_bounds__(256) void knn_kernel(const float* __restrict__ xin, int* __restrict__ idxout)
{
    __shared__ float sx[NN], sy[NN], sz[NN];         // 48 KB
    __shared__ unsigned sdist[NN];                   // 16 KB keys
    __shared__ unsigned shist[256];                  // 1 KB
    __shared__ unsigned scollv[256];                 // 1 KB boundary-group values
    __shared__ unsigned long long scoll64[128];      // 1 KB extracted (key,idx)
    __shared__ unsigned sres[2];                     // scan result: bin/K' (reused for W)
    __shared__ unsigned scnt[2];                     // collect counters
    const int tid = threadIdx.x;
    const int b  = blockIdx.x >> 8;                  // 256 blocks per batch
    const int q0 = (blockIdx.x & 255) * 16;          // 16 queries per block
    for (int i = tid; i < NN; i += 256) {
        const float4 rc = *reinterpret_cast<const float4*>(xin + (size_t)(b*NN + i) * CSTRIDE);
        sx[i] = rc.x; sy[i] = rc.y; sz[i] = rc.z;
    }

    for (int qq = 0; qq < 16; ++qq) {
        __syncthreads();                             // staging done / prev query fully consumed
        shist[tid] = 0;
        if (tid == 0) { scnt[0] = 0; scnt[1] = 0; }
        const int qi = q0 + qq;
        const float qx = sx[qi], qy = sy[qi], qz = sz[qi];
        const float nxx = -__fadd_rn(__fadd_rn(__fmul_rn(qx,qx), __fmul_rn(qy,qy)), __fmul_rn(qz,qz));
        __syncthreads();
        // pass 1: distances + keys + level-0 histogram
#pragma unroll
        for (int i = 0; i < NN/256; ++i) {
            const int m = tid + (i << 8);
            float cx = sx[m], cy = sy[m], cz = sz[m];
            float cw  = __fadd_rn(__fadd_rn(__fmul_rn(cx,cx), __fmul_rn(cy,cy)), __fmul_rn(cz,cz));
            float dot = __fadd_rn(__fadd_rn(__fmul_rn(qx,cx), __fmul_rn(qy,cy)), __fmul_rn(qz,cz));
            float pd  = __fsub_rn(__fsub_rn(nxx, __fmul_rn(-2.f, dot)), cw);
            unsigned u = fenc(pd);
            sdist[m] = u;
            atomicAdd(&shist[u >> 24], 1u);
        }
        __syncthreads();
        // scan level 0: find boundary bin b0 and remaining rank K1 (K=20)
        if (tid < 64) {
            const int base = 255 - tid*4;
            unsigned h0 = shist[base], h1 = shist[base-1], h2 = shist[base-2], h3 = shist[base-3];
            unsigned s = h0 + h1 + h2 + h3;
            unsigned c = s;
#pragma unroll
            for (int off = 1; off < 64; off <<= 1) { unsigned t = __shfl_up(c, off, 64); if (tid >= off) c += t; }
            unsigned cprev = c - s;
            if (c >= KK && cprev < KK) {
                unsigned cc = cprev; int bb = base;
                if (cc + h0 < KK) { cc += h0; bb = base-1;
                    if (cc + h1 < KK) { cc += h1; bb = base-2;
                        if (cc + h2 < KK) { cc += h2; bb = base-3; } } }
                sres[0] = (unsigned)bb; sres[1] = KK - cc;
            }
        }
        __syncthreads();
        const unsigned b0 = sres[0], K1 = sres[1];
        shist[tid] = 0;
        __syncthreads();
        // level 1 histogram within bin b0
#pragma unroll
        for (int i = 0; i < NN/256; ++i) {
            unsigned u = sdist[tid + (i << 8)];
            if ((u >> 24) == b0) atomicAdd(&shist[(u >> 16) & 255u], 1u);
        }
        __syncthreads();
        if (tid < 64) {
            const int base = 255 - tid*4;
            unsigned h0 = shist[base], h1 = shist[base-1], h2 = shist[base-2], h3 = shist[base-3];
            unsigned s = h0 + h1 + h2 + h3;
            unsigned c = s;
#pragma unroll
            for (int off = 1; off < 64; off <<= 1) { unsigned t = __shfl_up(c, off, 64); if (tid >= off) c += t; }
            unsigned cprev = c - s;
            if (c >= K1 && cprev < K1) {
                unsigned cc = cprev; int bb = base;
                if (cc + h0 < K1) { cc += h0; bb = base-1;
                    if (cc + h1 < K1) { cc += h1; bb = base-2;
                        if (cc + h2 < K1) { cc += h2; bb = base-3; } } }
                sres[0] = (unsigned)bb; sres[1] = K1 - cc;
            }
        }
        __syncthreads();
        const unsigned prefix16 = (b0 << 8) | sres[0];
        const unsigned K2 = sres[1];
        // collect boundary 16-bit-prefix group
#pragma unroll
        for (int i = 0; i < NN/256; ++i) {
            unsigned u = sdist[tid + (i << 8)];
            if ((u >> 16) == prefix16) {
                unsigned pos = atomicAdd(&scnt[0], 1u);
                if (pos < 256u) scollv[pos] = u;
            }
        }
        __syncthreads();
        // exact 20th key W: K2-th largest of collected (duplicate-safe rank test)
        {
            int cb = (int)scnt[0]; if (cb > 256) cb = 256;
            if (tid < cb) {
                unsigned v = scollv[tid];
                unsigned ng = 0, ne = 0;
                for (int j = 0; j < cb; ++j) {
                    unsigned w = scollv[j];
                    ng += (w > v); ne += (w == v);
                }
                if (ng < K2 && ng + ne >= K2) sres[0] = v;   // unique value; multi-writers write same v
            }
        }
        __syncthreads();
        const unsigned W = sres[0];
        // extract all keys >= W
#pragma unroll
        for (int i = 0; i < NN/256; ++i) {
            const int m = tid + (i << 8);
            unsigned u = sdist[m];
            if (u >= W) {
                unsigned pos = atomicAdd(&scnt[1], 1u);
                if (pos < 128u) scoll64[pos] = ((unsigned long long)u << 32) | (unsigned)(NN-1 - m);
            }
        }
        __syncthreads();
        // rank (desc by key, asc by idx) and write top-20
        {
            int c2 = (int)scnt[1]; if (c2 > 128) c2 = 128;
            if (tid < c2) {
                unsigned long long kv = scoll64[tid];
                int rank = 0;
                for (int j = 0; j < c2; ++j) rank += (scoll64[j] > kv);
                if (rank < KK) {
                    int* op = idxout + ((size_t)(b*NN + qi)) * KK;
                    op[rank] = (NN-1) - (int)(kv & 0xFFFFFFFFull);
                }
            }
        }
    }
}

// ---------------- stage 1 pass A: conv1 (8->64) stats only (f64 accum) ----------------
__global__ __launch_bounds__(64) void s1a_kernel(const float* __restrict__ x, const int* __restrict__ idx,
    const float* __restrict__ w1, double* __restrict__ ssum, double* __restrict__ ssq)
{
    const int lane = threadIdx.x;
    float wr[8];
#pragma unroll
    for (int c = 0; c < 8; ++c) wr[c] = w1[lane*8 + c];
    const int g0 = blockIdx.x * 8;            // global row (b*NN+n), 8 rows per block
    const int b = g0 / NN;
    double lsum = 0.0, lsq = 0.0;
    for (int ni = 0; ni < 8; ++ni) {
        const int g = g0 + ni;
        const float4 ct = *reinterpret_cast<const float4*>(x + (size_t)g*4);
        for (int k = 0; k < KK; ++k) {
            const int j = idx[(size_t)g*KK + k] & NMASK;
            const float4 nb = *reinterpret_cast<const float4*>(x + (size_t)(b*NN + j)*4);
            float o1 = wr[0]*(nb.x-ct.x) + wr[1]*(nb.y-ct.y) + wr[2]*(nb.z-ct.z) + wr[3]*(nb.w-ct.w)
                     + wr[4]*ct.x + wr[5]*ct.y + wr[6]*ct.z + wr[7]*ct.w;
            lsum += (double)o1; lsq += (double)o1*(double)o1;
        }
    }
    atomicAdd(&ssum[b*64+lane], lsum);
    atomicAdd(&ssq [b*64+lane], lsq);
}

// ---------------- stage 1 pass B: recompute conv1, norm+lrelu, conv2 (64->64), stats2 + max_k ----------------
__global__ __launch_bounds__(64) void s1b_kernel(const float* __restrict__ x, const int* __restrict__ idx,
    const float* __restrict__ w1, const float* __restrict__ w2,
    const float* __restrict__ m1, const float* __restrict__ r1,
    float* __restrict__ xraw, double* __restrict__ ssum, double* __restrict__ ssq)
{
    __shared__ float sh[64];
    const int lane = threadIdx.x;
    float wr1[8];
#pragma unroll
    for (int c = 0; c < 8; ++c) wr1[c] = w1[lane*8 + c];
    float wr2[64];
#pragma unroll
    for (int c = 0; c < 64; ++c) wr2[c] = w2[lane*64 + c];
    const int g0 = blockIdx.x * 8;
    const int b = g0 / NN;
    const float mm = m1[b*64+lane], rr = r1[b*64+lane];
    double lsum = 0.0, lsq = 0.0;
    for (int ni = 0; ni < 8; ++ni) {
        const int g = g0 + ni;
        const float4 ct = *reinterpret_cast<const float4*>(x + (size_t)g*4);
        float vmax = -INFINITY;
        for (int k = 0; k < KK; ++k) {
            const int j = idx[(size_t)g*KK + k] & NMASK;
            const float4 nb = *reinterpret_cast<const float4*>(x + (size_t)(b*NN + j)*4);
            float o1 = wr1[0]*(nb.x-ct.x) + wr1[1]*(nb.y-ct.y) + wr1[2]*(nb.z-ct.z) + wr1[3]*(nb.w-ct.w)
                     + wr1[4]*ct.x + wr1[5]*ct.y + wr1[6]*ct.z + wr1[7]*ct.w;
            float h = lrelu_f((o1 - mm) * rr);
            __syncthreads();                  // protect prior reads
            sh[lane] = h;
            __syncthreads();
            float acc = 0.f;
#pragma unroll
            for (int c = 0; c < 64; c += 4) {
                const float4 hv = *reinterpret_cast<const float4*>(&sh[c]);
                acc += wr2[c]*hv.x + wr2[c+1]*hv.y + wr2[c+2]*hv.z + wr2[c+3]*hv.w;
            }
            vmax = fmaxf(vmax, acc);
            lsum += (double)acc; lsq += (double)acc*(double)acc;
        }
        xraw[(size_t)g*64 + lane] = vmax;
    }
    atomicAdd(&ssum[b*64+lane], lsum);
    atomicAdd(&ssq [b*64+lane], lsq);
}

// ---------------- gather conv (128->64) stats only (conv3 pass A) ----------------
__global__ __launch_bounds__(64) void s2a_kernel(const float* __restrict__ xin, const int* __restrict__ idx,
    const float* __restrict__ w, double* __restrict__ ssum, double* __restrict__ ssq)
{
    __shared__ float sf[128];
    const int lane = threadIdx.x;
    float wr[128];
#pragma unroll
    for (int c = 0; c < 128; ++c) wr[c] = w[lane*128 + c];
    const int g0 = blockIdx.x * 8;
    const int b = g0 / NN;
    double lsum = 0.0, lsq = 0.0;
    for (int ni = 0; ni < 8; ++ni) {
        const int g = g0 + ni;
        const float ctl = xin[(size_t)g*64 + lane];
        for (int k = 0; k < KK; ++k) {
            const int j = idx[(size_t)g*KK + k] & NMASK;
            const float nbl = xin[(size_t)(b*NN + j)*64 + lane];
            __syncthreads();
            sf[lane] = nbl - ctl;
            sf[64+lane] = ctl;
            __syncthreads();
            float acc = 0.f;
#pragma unroll
            for (int c = 0; c < 128; c += 4) {
                const float4 fv = *reinterpret_cast<const float4*>(&sf[c]);
                acc += wr[c]*fv.x + wr[c+1]*fv.y + wr[c+2]*fv.z + wr[c+3]*fv.w;
            }
            lsum += (double)acc; lsq += (double)acc*(double)acc;
        }
    }
    atomicAdd(&ssum[b*64+lane], lsum);
    atomicAdd(&ssq [b*64+lane], lsq);
}

// ---------------- stage 2 pass B: recompute conv3, norm+lrelu, conv4 (64->64), stats4 + max_k ----------------
__global__ __launch_bounds__(64) void s2b_kernel(const float* __restrict__ xin, const int* __restrict__ idx,
    const float* __restrict__ w3, const float* __restrict__ w4,
    const float* __restrict__ m3, const float* __restrict__ r3,
    float* __restrict__ xraw, double* __restrict__ ssum, double* __restrict__ ssq)
{
    __shared__ float sf[128];
    __shared__ float sh[64];
    const int lane = threadIdx.x;
    float wr3[128];
#pragma unroll
    for (int c = 0; c < 128; ++c) wr3[c] = w3[lane*128 + c];
    float wr4[64];
#pragma unroll
    for (int c = 0; c < 64; ++c) wr4[c] = w4[lane*64 + c];
    const int g0 = blockIdx.x * 8;
    const int b = g0 / NN;
    const float mm = m3[b*64+lane], rr = r3[b*64+lane];
    double lsum = 0.0, lsq = 0.0;
    for (int ni = 0; ni < 8; ++ni) {
        const int g = g0 + ni;
        const float ctl = xin[(size_t)g*64 + lane];
        float vmax = -INFINITY;
        for (int k = 0; k < KK; ++k) {
            const int j = idx[(size_t)g*KK + k] & NMASK;
            const float nbl = xin[(size_t)(b*NN + j)*64 + lane];
            __syncthreads();
            sf[lane] = nbl - ctl;
            sf[64+lane] = ctl;
            __syncthreads();
            float o3 = 0.f;
#pragma unroll
            for (int c = 0; c < 128; c += 4) {
                const float4 fv = *reinterpret_cast<const float4*>(&sf[c]);
                o3 += wr3[c]*fv.x + wr3[c+1]*fv.y + wr3[c+2]*fv.z + wr3[c+3]*fv.w;
            }
            float h = lrelu_f((o3 - mm) * rr);
            __syncthreads();
            sh[lane] = h;
            __syncthreads();
            float acc = 0.f;
#pragma unroll
            for (int c = 0; c < 64; c += 4) {
                const float4 hv = *reinterpret_cast<const float4*>(&sh[c]);
                acc += wr4[c]*hv.x + wr4[c+1]*hv.y + wr4[c+2]*hv.z + wr4[c+3]*hv.w;
            }
            vmax = fmaxf(vmax, acc);
            lsum += (double)acc; lsq += (double)acc*(double)acc;
        }
        xraw[(size_t)g*64 + lane] = vmax;
    }
    atomicAdd(&ssum[b*64+lane], lsum);
    atomicAdd(&ssq [b*64+lane], lsq);
}

// ---------------- stage 3: conv5 (128->64) single pass: stats5 + max_k ----------------
__global__ __launch_bounds__(64) void s3_kernel(const float* __restrict__ xin, const int* __restrict__ idx,
    const float* __restrict__ w, float* __restrict__ xraw, double* __restrict__ ssum, double* __restrict__ ssq)
{
    __shared__ float sf[128];
    const int lane = threadIdx.x;
    float wr[128];
#pragma unroll
    for (int c = 0; c < 128; ++c) wr[c] = w[lane*128 + c];
    const int g0 = blockIdx.x * 8;
    const int b = g0 / NN;
    double lsum = 0.0, lsq = 0.0;
    for (int ni = 0; ni < 8; ++ni) {
        const int g = g0 + ni;
        const float ctl = xin[(size_t)g*64 + lane];
        float vmax = -INFINITY;
        for (int k = 0; k < KK; ++k) {
            const int j = idx[(size_t)g*KK + k] & NMASK;
            const float nbl = xin[(size_t)(b*NN + j)*64 + lane];
            __syncthreads();
            sf[lane] = nbl - ctl;
            sf[64+lane] = ctl;
            __syncthreads();
            float acc = 0.f;
#pragma unroll
            for (int c = 0; c < 128; c += 4) {
                const float4 fv = *reinterpret_cast<const float4*>(&sf[c]);
                acc += wr[c]*fv.x + wr[c+1]*fv.y + wr[c+2]*fv.z + wr[c+3]*fv.w;
            }
            vmax = fmaxf(vmax, acc);
            lsum += (double)acc; lsq += (double)acc*(double)acc;
        }
        xraw[(size_t)g*64 + lane] = vmax;
    }
    atomicAdd(&ssum[b*64+lane], lsum);
    atomicAdd(&ssq [b*64+lane], lsq);
}

// ---------------- stats finalize: f64 sum/sq -> f32 mean/rstd ----------------
__global__ void fin_kernel(const double* __restrict__ ssum, const double* __restrict__ ssq,
                           float* __restrict__ meanp, float* __restrict__ rstdp, int total, double invn)
{
    int t = blockIdx.x*256 + threadIdx.x;
    if (t >= total) return;
    double m = ssum[t]*invn;
    double v = ssq[t]*invn - m*m;
    meanp[t] = (float)m;
    rstdp[t] = (float)(1.0 / sqrt(v + 1e-5));
}

// ---------------- in-place finalize of x raw max: x = lrelu((x-m)*r) ----------------
__global__ void finx_kernel(float* __restrict__ xv, const float* __restrict__ m, const float* __restrict__ r)
{
    int t = blockIdx.x*256 + threadIdx.x;   // B*NN*64 = 1048576
    int c = t & 63;
    int b = t >> 18;                        // NN*64 = 2^18
    float v = xv[t];
    xv[t] = lrelu_f((v - m[b*64+c]) * r[b*64+c]);
}

// weight transpose: wT[c*O + o] = w[o*rs + off + c]
__global__ void transw_kernel(const float* __restrict__ w, float* __restrict__ wT, int O, int C, int rs, int off)
{
    int t = blockIdx.x*256 + threadIdx.x;
    if (t >= O*C) return;
    int o = t % O, c = t / O;
    wT[t] = w[(size_t)o*rs + off + c];
}

// conv6: 192->1024 over n, reduced on the fly (sum/sumsq/max per (b,o)); output never materialized
__global__ __launch_bounds__(256) void conv6_kernel(
    const float* __restrict__ x1, const float* __restrict__ x2, const float* __restrict__ x3,
    const float* __restrict__ wT, double* __restrict__ s6sum, double* __restrict__ s6sq, unsigned* __restrict__ s6max)
{
    __shared__ float si[32][192];
    const int b = blockIdx.z, nbase = blockIdx.x*32;
    const int o = blockIdx.y*256 + threadIdx.x;
    for (int i = threadIdx.x; i < 32*192; i += 256) {
        int nl = i/192, c = i%192;
        size_t base = (size_t)(b*NN + nbase + nl)*64;
        si[nl][c] = (c < 64) ? x1[base + c] : (c < 128) ? x2[base + c - 64] : x3[base + c - 128];
    }
    __syncthreads();
    float acc[32];
#pragma unroll
    for (int n = 0; n < 32; ++n) acc[n] = 0.f;
    for (int c = 0; c < 192; ++c) {
        float wv = wT[(size_t)c*1024 + o];
#pragma unroll
        for (int n = 0; n < 32; ++n) acc[n] = fmaf(wv, si[n][c], acc[n]);
    }
    double ps = 0.0, pq = 0.0; float pm = -INFINITY;
#pragma unroll
    for (int n = 0; n < 32; ++n) { ps += (double)acc[n]; pq += (double)acc[n]*(double)acc[n]; pm = fmaxf(pm, acc[n]); }
    atomicAdd(&s6sum[b*1024+o], ps);
    atomicAdd(&s6sq [b*1024+o], pq);
    atomicMax(&s6max[b*1024+o], fenc(pm));
}

__global__ void gfin_kernel(const double* __restrict__ s6sum, const double* __restrict__ s6sq,
                            const unsigned* __restrict__ s6max, float* __restrict__ g)
{
    int t = blockIdx.x*256 + threadIdx.x;   // 4096
    double m = s6sum[t] * (1.0/4096.0);
    double v = s6sq[t] * (1.0/4096.0) - m*m;
    float rs = (float)(1.0 / sqrt(v + 1e-5));
    g[t] = lrelu_f((fdec(s6max[t]) - (float)m) * rs);   // lrelu∘norm commutes with max over n
}

// gbias[b][o] = sum_{c<1024} w7[o][c] * g[b][c]
__global__ __launch_bounds__(256) void gbias_kernel(const float* __restrict__ w7, const float* __restrict__ g,
                                                    float* __restrict__ gbias)
{
    const int b = blockIdx.y;
    const int o = blockIdx.x*256 + threadIdx.x;
    const float* wr = w7 + (size_t)o*1216;
    const float* gv = g + b*1024;
    float acc = 0.f;
    for (int c = 0; c < 1024; c += 4) {
        float4 wv = *reinterpret_cast<const float4*>(&wr[c]);
        float4 gg = *reinterpret_cast<const float4*>(&gv[c]);
        acc = fmaf(wv.x, gg.x, fmaf(wv.y, gg.y, fmaf(wv.z, gg.z, fmaf(wv.w, gg.w, acc))));
    }
    gbias[b*512+o] = acc;
}

// conv7 pass A: 192(cat)+gbias -> 512, stats only (no store)
__global__ __launch_bounds__(256) void conv7a_kernel(
    const float* __restrict__ x1, const float* __restrict__ x2, const float* __restrict__ x3,
    const float* __restrict__ wT, const float* __restrict__ gbias,
    double* __restrict__ ssum, double* __restrict__ ssq)
{
    __shared__ float si[32][192];
    const int b = blockIdx.z, nbase = blockIdx.x*32;
    const int o = blockIdx.y*256 + threadIdx.x;
    for (int i = threadIdx.x; i < 32*192; i += 256) {
        int nl = i/192, c = i%192;
        size_t base = (size_t)(b*NN + nbase + nl)*64;
        si[nl][c] = (c < 64) ? x1[base + c] : (c < 128) ? x2[base + c - 64] : x3[base + c - 128];
    }
    __syncthreads();
    float acc[32];
    const float gb = gbias[b*512 + o];
#pragma unroll
    for (int n = 0; n < 32; ++n) acc[n] = gb;
    for (int c = 0; c < 192; ++c) {
        float wv = wT[(size_t)c*512 + o];
#pragma unroll
        for (int n = 0; n < 32; ++n) acc[n] = fmaf(wv, si[n][c], acc[n]);
    }
    double ps = 0.0, pq = 0.0;
#pragma unroll
    for (int n = 0; n < 32; ++n) { ps += (double)acc[n]; pq += (double)acc[n]*(double)acc[n]; }
    atomicAdd(&ssum[b*512+o], ps);
    atomicAdd(&ssq [b*512+o], pq);
}

// conv7+conv8 fused pass B: recompute conv7, norm+lrelu -> h7 (LDS), conv8 -> out8 + stats8
__global__ __launch_bounds__(256) void conv78_kernel(
    const float* __restrict__ x1, const float* __restrict__ x2, const float* __restrict__ x3,
    const float* __restrict__ wT7, const float* __restrict__ wT8, const float* __restrict__ gbias,
    const float* __restrict__ m7, const float* __restrict__ r7,
    float* __restrict__ out8, double* __restrict__ ssum, double* __restrict__ ssq)
{
    __shared__ float si[16][192];    // 12 KB
    __shared__ float h7[16][512];    // 32 KB
    const int b = blockIdx.y, nbase = blockIdx.x*16;
    const int tid = threadIdx.x;
    for (int i = tid; i < 16*192; i += 256) {
        int nl = i/192, c = i%192;
        size_t base = (size_t)(b*NN + nbase + nl)*64;
        si[nl][c] = (c < 64) ? x1[base + c] : (c < 128) ? x2[base + c - 64] : x3[base + c - 128];
    }
    __syncthreads();
#pragma unroll
    for (int oo = 0; oo < 512; oo += 256) {
        const int o = oo + tid;
        const float gb = gbias[b*512+o], mm = m7[b*512+o], rr = r7[b*512+o];
        float acc[16];
#pragma unroll
        for (int n = 0; n < 16; ++n) acc[n] = gb;
        for (int c = 0; c < 192; ++c) {
            float wv = wT7[(size_t)c*512 + o];
#pragma unroll
            for (int n = 0; n < 16; ++n) acc[n] = fmaf(wv, si[n][c], acc[n]);
        }
#pragma unroll
        for (int n = 0; n < 16; ++n) h7[n][o] = lrelu_f((acc[n] - mm) * rr);
    }
    __syncthreads();
    const int o = tid;
    float acc8[16];
#pragma unroll
    for (int n = 0; n < 16; ++n) acc8[n] = 0.f;
    for (int c = 0; c < 512; ++c) {
        float wv = wT8[(size_t)c*256 + o];
#pragma unroll
        for (int n = 0; n < 16; ++n) acc8[n] = fmaf(wv, h7[n][c], acc8[n]);
    }
    double ps = 0.0, pq = 0.0;
#pragma unroll
    for (int n = 0; n < 16; ++n) {
        out8[(size_t)(b*NN + nbase + n)*256 + o] = acc8[n];
        ps += (double)acc8[n]; pq += (double)acc8[n]*(double)acc8[n];
    }
    atomicAdd(&ssum[b*256+o], ps);
    atomicAdd(&ssq [b*256+o], pq);
}

// conv9: 256 -> 2, output (B,N,2)
__global__ __launch_bounds__(256) void conv9_kernel(const float* __restrict__ in8,
    const float* __restrict__ meanp, const float* __restrict__ rstdp,
    const float* __restrict__ w9, float* __restrict__ outp)
{
    const int lane = threadIdx.x & 63, wv = threadIdx.x >> 6;
    const int ng = blockIdx.x*4 + wv;
    const int b = ng / NN;
    const int c0 = lane*4;
    const float4 v4 = *reinterpret_cast<const float4*>(&in8[(size_t)ng*256 + c0]);
    float vv[4] = {v4.x, v4.y, v4.z, v4.w};
    float a0 = 0.f, a1 = 0.f;
#pragma unroll
    for (int i = 0; i < 4; ++i) {
        int c = c0 + i;
        float a = lrelu_f((vv[i] - meanp[b*256+c]) * rstdp[b*256+c]);
        a0 = fmaf(w9[c],     a, a0);
        a1 = fmaf(w9[256+c], a, a1);
    }
#pragma unroll
    for (int off = 32; off > 0; off >>= 1) {
        a0 += __shfl_down(a0, off, 64);
        a1 += __shfl_down(a1, off, 64);
    }
    if (lane == 0) { outp[(size_t)ng*2 + 0] = a0; outp[(size_t)ng*2 + 1] = a1; }
}

extern "C" void kernel_launch(void* const* d_in, const int* in_sizes, int n_in,
                              void* d_out, int out_size, void* d_ws, size_t ws_size,
                              hipStream_t stream)
{
    const float* x  = (const float*)d_in[0];
    const float* w1 = (const float*)d_in[1];
    const float* w2 = (const float*)d_in[2];
    const float* w3 = (const float*)d_in[3];
    const float* w4 = (const float*)d_in[4];
    const float* w5 = (const float*)d_in[5];
    const float* w6 = (const float*)d_in[6];
    const float* w7 = (const float*)d_in[7];
    const float* w8 = (const float*)d_in[8];
    const float* w9 = (const float*)d_in[9];
    float* outp = (float*)d_out;

    char* ws = (char*)d_ws;
    size_t off = 0;
    auto alloc = [&](size_t bytes) -> void* {
        void* p = ws + off;
        off = (off + bytes + 255) & ~(size_t)255;
        return p;
    };
    // f64 stats block + u32 max block: contiguous, one memset
    double* dstats = (double*)alloc((size_t)16896 * 8);      // 135168 B (multiple of 256)
    unsigned* u6max = (unsigned*)alloc((size_t)4096 * 4);    // 16384 B, contiguous after dstats
    float* fstats = (float*)alloc((size_t)14848 * 4);        // means/rstds/g/gbias
    int*   idxb  = (int*)  alloc((size_t)TPOS * 4);          // 1.31 MB
    float* wT6   = (float*)alloc((size_t)1024*192*4);
    float* wT7   = (float*)alloc((size_t)512*192*4);
    float* wT8   = (float*)alloc((size_t)256*512*4);
    float* x1v   = (float*)alloc((size_t)BB*NN*64*4);
    float* x2v   = (float*)alloc((size_t)BB*NN*64*4);
    float* x3v   = (float*)alloc((size_t)BB*NN*64*4);
    float* out8  = (float*)alloc((size_t)BB*NN*256*4);       // total ~32.6 MB

    // dstats layout (doubles): d1..d5 at s*512 (sum256|sq256); d6 @2560 (4096|4096);
    // d7 @10752 (2048|2048); d8 @14848 (1024|1024)
    double* d1 = dstats;           double* d2 = dstats + 512;
    double* d3 = dstats + 1024;    double* d4 = dstats + 1536;
    double* d5 = dstats + 2048;
    double* d6sum = dstats + 2560; double* d6sq = d6sum + 4096;
    double* d7sum = dstats + 10752; double* d7sq = d7sum + 2048;
    double* d8sum = dstats + 14848; double* d8sq = d8sum + 1024;
    // fstats layout (floats): m/r for s1..s5 at s*512; g @2560; m7 @6656; r7 @8704; gbias @10752; m8 @12800; r8 @13824
    float* m1 = fstats;        float* r1 = fstats + 256;
    float* m2 = fstats + 512;  float* r2 = fstats + 768;
    float* m3 = fstats + 1024; float* r3 = fstats + 1280;
    float* m4 = fstats + 1536; float* r4 = fstats + 1792;
    float* m5 = fstats + 2048; float* r5 = fstats + 2304;
    float* g  = fstats + 2560;
    float* m7 = fstats + 6656; float* r7 = fstats + 8704;
    float* gbias = fstats + 10752;
    float* m8 = fstats + 12800; float* r8 = fstats + 13824;

    hipMemsetAsync(dstats, 0, (size_t)16896*8 + (size_t)4096*4, stream);  // f64 stats + u6max

    transw_kernel<<<768, 256, 0, stream>>>(w6, wT6, 1024, 192, 192, 0);
    transw_kernel<<<384, 256, 0, stream>>>(w7, wT7, 512, 192, 1216, 1024);
    transw_kernel<<<512, 256, 0, stream>>>(w8, wT8, 256, 512, 512, 0);

    // ---- stage 1 ----
    knn_kernel<4><<<1024, 256, 0, stream>>>(x, idxb);
    s1a_kernel<<<2048, 64, 0, stream>>>(x, idxb, w1, d1, d1+256);
    fin_kernel<<<1, 256, 0, stream>>>(d1, d1+256, m1, r1, 256, 1.0/81920.0);
    s1b_kernel<<<2048, 64, 0, stream>>>(x, idxb, w1, w2, m1, r1, x1v, d2, d2+256);
    fin_kernel<<<1, 256, 0, stream>>>(d2, d2+256, m2, r2, 256, 1.0/81920.0);
    finx_kernel<<<4096, 256, 0, stream>>>(x1v, m2, r2);

    // ---- stage 2 ----
    knn_kernel<64><<<1024, 256, 0, stream>>>(x1v, idxb);
    s2a_kernel<<<2048, 64, 0, stream>>>(x1v, idxb, w3, d3, d3+256);
    fin_kernel<<<1, 256, 0, stream>>>(d3, d3+256, m3, r3, 256, 1.0/81920.0);
    s2b_kernel<<<2048, 64, 0, stream>>>(x1v, idxb, w3, w4, m3, r3, x2v, d4, d4+256);
    fin_kernel<<<1, 256, 0, stream>>>(d4, d4+256, m4, r4, 256, 1.0/81920.0);
    finx_kernel<<<4096, 256, 0, stream>>>(x2v, m4, r4);

    // ---- stage 3 ----
    knn_kernel<64><<<1024, 256, 0, stream>>>(x2v, idxb);
    s3_kernel<<<2048, 64, 0, stream>>>(x2v, idxb, w5, x3v, d5, d5+256);
    fin_kernel<<<1, 256, 0, stream>>>(d5, d5+256, m5, r5, 256, 1.0/81920.0);
    finx_kernel<<<4096, 256, 0, stream>>>(x3v, m5, r5);

    // ---- global feature ----
    conv6_kernel<<<dim3(128, 4, 4), 256, 0, stream>>>(x1v, x2v, x3v, wT6, d6sum, d6sq, u6max);
    gfin_kernel<<<16, 256, 0, stream>>>(d6sum, d6sq, u6max, g);
    gbias_kernel<<<dim3(2, 4), 256, 0, stream>>>(w7, g, gbias);

    // ---- head ----
    conv7a_kernel<<<dim3(128, 2, 4), 256, 0, stream>>>(x1v, x2v, x3v, wT7, gbias, d7sum, d7sq);
    fin_kernel<<<8, 256, 0, stream>>>(d7sum, d7sq, m7, r7, 2048, 1.0/4096.0);
    conv78_kernel<<<dim3(256, 4), 256, 0, stream>>>(x1v, x2v, x3v, wT7, wT8, gbias, m7, r7, out8, d8sum, d8sq);
    fin_kernel<<<4, 256, 0, stream>>>(d8sum, d8sq, m8, r8, 1024, 1.0/4096.0);
    conv9_kernel<<<4096, 256, 0, stream>>>(out8, m8, r8, w9, outp);
}